// Round 8
// baseline (1659.790 us; speedup 1.0000x reference)
//
#include <hip/hip_runtime.h>
#include <hip/hip_bf16.h>

#define N_PTS 1048576
#define RES 192
#define R3 (RES*RES*RES)
#define NCH 28

#define BXC 32
#define BYC 8
#define BZC 8
#define CX (RES/BXC)              // 6
#define CY (RES/BYC)              // 24
#define CZ (RES/BZC)              // 24
#define NCELLS (CX*CY*CZ)         // 3456
#define NPRIV 16                  // privatization for real cells
#define HIST_ENTRIES (NCELLS*NPRIV)   // 55296

// Returns cell id in [0, NCELLS) or NCELLS for masked-out points.
__device__ __forceinline__ unsigned point_key(float xx, float xy, float xz) {
    if (fabsf(xx) < 1.5f && fabsf(xy) < 1.5f && fabsf(xz) < 1.5f) {
        float cx = fminf(fmaxf(xx / 1.5f, -1.f), 1.f);
        float cy = fminf(fmaxf(xy / 1.5f, -1.f), 1.f);
        float cz = fminf(fmaxf(xz / 1.5f, -1.f), 1.f);
        int ix = (int)(((cx + 1.f) * 0.5f) * (float)(RES - 1));
        int iy = (int)(((cy + 1.f) * 0.5f) * (float)(RES - 1));
        int iz = (int)(((cz + 1.f) * 0.5f) * (float)(RES - 1));
        ix = min(ix, RES - 1); iy = min(iy, RES - 1); iz = min(iz, RES - 1);
        return ((unsigned)(iz / BZC) * CY + (unsigned)(iy / BYC)) * CX + (unsigned)(ix / BXC);
    }
    return (unsigned)NCELLS;
}

__global__ __launch_bounds__(256) void k_count(const float* __restrict__ x,
                                               unsigned* __restrict__ key,
                                               unsigned* __restrict__ hist) {
    unsigned i = blockIdx.x * 256 + threadIdx.x;
    if (i >= N_PTS) return;
    float xx = x[3*i+0], xy = x[3*i+1], xz = x[3*i+2];
    unsigned k = point_key(xx, xy, xz);
    key[i] = k;
    if (k < (unsigned)NCELLS)
        atomicAdd(&hist[k * NPRIV + (blockIdx.x & (NPRIV - 1))], 1u);
    // masked points: no histogram slot, no perm slot — output is pre-zeroed.
}

// Single-block exclusive scan over HIST_ENTRIES (55296) entries.
__global__ __launch_bounds__(1024) void k_scan(unsigned* __restrict__ hist) {
    __shared__ unsigned s[1024];
    const int TOT = HIST_ENTRIES;
    const int CHUNK = TOT / 1024;   // 54
    int t = threadIdx.x;
    int beg = t * CHUNK;
    int end = beg + CHUNK;
    unsigned sum = 0;
    for (int u = beg; u < end; ++u) sum += hist[u];
    s[t] = sum;
    __syncthreads();
    for (int off = 1; off < 1024; off *= 2) {
        unsigned v = (t >= off) ? s[t - off] : 0u;
        __syncthreads();
        s[t] += v;
        __syncthreads();
    }
    unsigned run = (t > 0) ? s[t - 1] : 0u;
    for (int u = beg; u < end; ++u) {
        unsigned h = hist[u];
        hist[u] = run;
        run += h;
    }
}

__global__ __launch_bounds__(256) void k_scatter(const unsigned* __restrict__ key,
                                                 unsigned* __restrict__ hist,
                                                 unsigned* __restrict__ perm) {
    unsigned i = blockIdx.x * 256 + threadIdx.x;
    if (i >= N_PTS) return;
    unsigned k = key[i];
    if (k >= (unsigned)NCELLS) return;   // masked: not in perm
    unsigned pos = atomicAdd(&hist[k * NPRIV + (blockIdx.x & (NPRIV - 1))], 1u);
    if (pos < (unsigned)N_PTS) perm[pos] = i;
}

// ---------------------------------------------------------------------------
// Corner-parallel main: 4 threads per point; thread t owns the (y,z)-corner
// (t&1 -> y1, t&2 -> z1) and x-lerps it: v = wA*g[oA] + wB*g[oB].
// XCD-aware bijective block swizzle: launched block l executes original block
// (l&7)*(nwg/8) + (l>>3). HW assigns l -> XCD l%8, so each XCD processes a
// CONTIGUOUS slice of the sorted point order -> each spatial cell's grid
// lines live in exactly one XCD L2 (they were replicated into up to 8 L2s
// before, inflating FETCH 1.15 -> 1.93 GB in round 7).
// ---------------------------------------------------------------------------
__global__ __launch_bounds__(256, 4) void k_main4(const float* __restrict__ x,
                                                  const float* __restrict__ dvec,
                                                  const float* __restrict__ grid,
                                                  const unsigned* __restrict__ perm,
                                                  float* __restrict__ out) {
    unsigned cpx  = gridDim.x >> 3;                      // 2048
    unsigned orig = (blockIdx.x & 7) * cpx + (blockIdx.x >> 3);
    unsigned tid = orig * 256 + threadIdx.x;
    unsigned j = tid >> 2;        // sorted slot
    unsigned t = tid & 3;         // corner-pair id
    if (j >= (unsigned)N_PTS) return;
    unsigned i = perm[j];
    if (i >= (unsigned)N_PTS) return;   // sentinel (masked slot) / defensive

    float xx = x[3*i+0], xy = x[3*i+1], xz = x[3*i+2];

    float cx = fminf(fmaxf(xx / 1.5f, -1.f), 1.f);
    float cy = fminf(fmaxf(xy / 1.5f, -1.f), 1.f);
    float cz = fminf(fmaxf(xz / 1.5f, -1.f), 1.f);
    float px = ((cx + 1.f) * 0.5f) * (float)(RES - 1);
    float py = ((cy + 1.f) * 0.5f) * (float)(RES - 1);
    float pz = ((cz + 1.f) * 0.5f) * (float)(RES - 1);
    float fx = floorf(px), fy = floorf(py), fz = floorf(pz);
    float wx = px - fx, wy = py - fy, wz = pz - fz;
    int ix0 = min((int)fx, RES - 1);
    int iy0 = min((int)fy, RES - 1);
    int iz0 = min((int)fz, RES - 1);
    int ix1 = min(ix0 + 1, RES - 1);
    int iy1 = min(iy0 + 1, RES - 1);
    int iz1 = min(iz0 + 1, RES - 1);

    int o000 = (iz0 * RES + iy0) * RES + ix0;
    int dX = ix1 - ix0;
    int dY = (iy1 - iy0) * RES;
    int dZ = (iz1 - iz0) * RES * RES;

    float mx = 1.f - wx, my = 1.f - wy, mz = 1.f - wz;

    // This thread's (y,z) corner:
    int   oA  = o000 + ((t & 1) ? dY : 0) + ((t & 2) ? dZ : 0);
    int   oB  = oA + dX;
    float wyz = ((t & 1) ? wy : my) * ((t & 2) ? wz : mz);
    float wA  = mx * wyz;
    float wB  = wx * wyz;

    float dx = dvec[3*i+0], dy = dvec[3*i+1], dz = dvec[3*i+2];
    float B[9];
    B[0] = 0.282095f;
    B[1] = -0.488603f * dy;
    B[2] =  0.488603f * dz;
    B[3] = -0.488603f * dx;
    B[4] =  1.092548f * dx * dy;
    B[5] = -1.092548f * dy * dz;
    B[6] =  0.315392f * (2.f * dz * dz - dx * dx - dy * dy);
    B[7] = -1.092548f * dx * dz;
    B[8] =  0.546274f * (dx * dx - dy * dy);

    const float* g = grid;
    float s  = wA * g[oA] + wB * g[oB];   // channel 0 partial
    float p0 = 0.f, p1 = 0.f, p2 = 0.f;
    #pragma unroll
    for (int q = 0; q < 27; ++q) {        // channels 1..27, fully static
        g += R3;
        float v = wA * g[oA] + wB * g[oB];
        float term = B[q % 9] * v;        // static index -> registers
        if (q < 9)       p0 += term;
        else if (q < 18) p1 += term;
        else             p2 += term;
    }

    // Quad reduction (lanes t^1, t^2 are within the same quad).
    s  += __shfl_xor(s, 1);  s  += __shfl_xor(s, 2);
    p0 += __shfl_xor(p0, 1); p0 += __shfl_xor(p0, 2);
    p1 += __shfl_xor(p1, 1); p1 += __shfl_xor(p1, 2);
    p2 += __shfl_xor(p2, 1); p2 += __shfl_xor(p2, 2);

    if (t == 0) {
        out[i]               = fmaxf(s, 0.f);
        out[N_PTS + 3*i + 0] = p0;
        out[N_PTS + 3*i + 1] = p1;
        out[N_PTS + 3*i + 2] = p2;
    }
}

// Fallback (no workspace): one point per thread, unsorted, zeroes masked.
#define TRI(gp) (w000*(gp)[o000] + w001*(gp)[o001] + w010*(gp)[o010] + w011*(gp)[o011] \
               + w100*(gp)[o100] + w101*(gp)[o101] + w110*(gp)[o110] + w111*(gp)[o111])

__global__ __launch_bounds__(256, 4) void k_main_simple(const float* __restrict__ x,
                                                        const float* __restrict__ dvec,
                                                        const float* __restrict__ grid,
                                                        float* __restrict__ out) {
    unsigned i = blockIdx.x * 256 + threadIdx.x;
    if (i >= (unsigned)N_PTS) return;

    float xx = x[3*i+0], xy = x[3*i+1], xz = x[3*i+2];
    if (!(fabsf(xx) < 1.5f && fabsf(xy) < 1.5f && fabsf(xz) < 1.5f)) {
        out[i] = 0.f;
        out[N_PTS + 3*i + 0] = 0.f;
        out[N_PTS + 3*i + 1] = 0.f;
        out[N_PTS + 3*i + 2] = 0.f;
        return;
    }

    float cx = fminf(fmaxf(xx / 1.5f, -1.f), 1.f);
    float cy = fminf(fmaxf(xy / 1.5f, -1.f), 1.f);
    float cz = fminf(fmaxf(xz / 1.5f, -1.f), 1.f);
    float px = ((cx + 1.f) * 0.5f) * (float)(RES - 1);
    float py = ((cy + 1.f) * 0.5f) * (float)(RES - 1);
    float pz = ((cz + 1.f) * 0.5f) * (float)(RES - 1);
    float fx = floorf(px), fy = floorf(py), fz = floorf(pz);
    float wx = px - fx, wy = py - fy, wz = pz - fz;
    int ix0 = min((int)fx, RES - 1);
    int iy0 = min((int)fy, RES - 1);
    int iz0 = min((int)fz, RES - 1);
    int ix1 = min(ix0 + 1, RES - 1);
    int iy1 = min(iy0 + 1, RES - 1);
    int iz1 = min(iz0 + 1, RES - 1);

    int o000 = (iz0 * RES + iy0) * RES + ix0;
    int dX = ix1 - ix0;
    int dY = (iy1 - iy0) * RES;
    int dZ = (iz1 - iz0) * RES * RES;
    int o001 = o000 + dX,      o010 = o000 + dY,      o011 = o000 + dY + dX;
    int o100 = o000 + dZ,      o101 = o000 + dZ + dX;
    int o110 = o000 + dZ + dY, o111 = o000 + dZ + dY + dX;

    float mx = 1.f - wx, my = 1.f - wy, mz = 1.f - wz;
    float w000 = mx*my*mz, w001 = wx*my*mz, w010 = mx*wy*mz, w011 = wx*wy*mz;
    float w100 = mx*my*wz, w101 = wx*my*wz, w110 = mx*wy*wz, w111 = wx*wy*wz;

    const float* gp = grid;
    float sigma = fmaxf(TRI(gp), 0.f);

    float dx = dvec[3*i+0], dy = dvec[3*i+1], dz = dvec[3*i+2];
    float B[9];
    B[0] = 0.282095f;
    B[1] = -0.488603f * dy;
    B[2] =  0.488603f * dz;
    B[3] = -0.488603f * dx;
    B[4] =  1.092548f * dx * dy;
    B[5] = -1.092548f * dy * dz;
    B[6] =  0.315392f * (2.f * dz * dz - dx * dx - dy * dy);
    B[7] = -1.092548f * dx * dz;
    B[8] =  0.546274f * (dx * dx - dy * dy);

    float acc[3];
    #pragma unroll
    for (int gidx = 0; gidx < 3; ++gidx) {
        float a = 0.f;
        #pragma unroll
        for (int q = 0; q < 9; ++q) { gp += R3; a += B[q] * TRI(gp); }
        acc[gidx] = a;
    }

    out[i]               = sigma;
    out[N_PTS + 3*i + 0] = acc[0];
    out[N_PTS + 3*i + 1] = acc[1];
    out[N_PTS + 3*i + 2] = acc[2];
}

extern "C" void kernel_launch(void* const* d_in, const int* in_sizes, int n_in,
                              void* d_out, int out_size, void* d_ws, size_t ws_size,
                              hipStream_t stream) {
    // The voxel grid is the only huge input (28*192^3 elements); the two (N,3)
    // inputs keep their dict order: first = x (positions), second = d (dirs).
    int gi = -1;
    for (int i = 0; i < n_in; ++i) if (in_sizes[i] > 10000000) gi = i;
    int ai = -1, bi = -1;
    for (int i = 0; i < n_in; ++i) {
        if (i == gi) continue;
        if (ai < 0) ai = i; else if (bi < 0) bi = i;
    }
    const float* x    = (const float*)d_in[ai];
    const float* d    = (const float*)d_in[bi];
    const float* grid = (const float*)d_in[gi];
    float* out = (float*)d_out;

    const int NBLK = N_PTS / 256;   // 4096

    size_t need = (size_t)N_PTS * sizeof(unsigned) * 2 + (size_t)HIST_ENTRIES * sizeof(unsigned);
    bool do_sort = (d_ws != nullptr && ws_size >= need);

    // Masked points produce exactly 0: pre-zero the output and skip them.
    hipMemsetAsync(d_out, 0, (size_t)out_size * sizeof(float), stream);

    if (do_sort) {
        unsigned* perm = (unsigned*)d_ws;
        unsigned* key  = perm + N_PTS;
        unsigned* hist = key + N_PTS;
        hipMemsetAsync(hist, 0, HIST_ENTRIES * sizeof(unsigned), stream);
        hipMemsetAsync(perm, 0xFF, N_PTS * sizeof(unsigned), stream);   // sentinel
        k_count<<<NBLK, 256, 0, stream>>>(x, key, hist);
        k_scan<<<1, 1024, 0, stream>>>(hist);
        k_scatter<<<NBLK, 256, 0, stream>>>(key, hist, perm);
        k_main4<<<4 * NBLK, 256, 0, stream>>>(x, d, grid, perm, out);
    } else {
        k_main_simple<<<NBLK, 256, 0, stream>>>(x, d, grid, out);
    }
}

// Round 11
// 1610.654 us; speedup vs baseline: 1.0305x; 1.0305x over previous
//
#include <hip/hip_runtime.h>
#include <hip/hip_bf16.h>

#define N_PTS 1048576
#define RES 192
#define R3 (RES*RES*RES)
#define NCH 28

#define BXC 32
#define BYC 8
#define BZC 8
#define CX (RES/BXC)              // 6
#define CY (RES/BYC)              // 24
#define CZ (RES/BZC)              // 24
#define NCELLS (CX*CY*CZ)         // 3456
#define NPRIV 16                  // privatization for real cells
#define HIST_ENTRIES (NCELLS*NPRIV)   // 55296

#define MAIN_BLOCKS 4096          // fixed grid; 512 blocks per XCD
#define BPX_SHIFT 9               // blocks per XCD = 512 = 1<<9

// Returns cell id in [0, NCELLS) or NCELLS for masked-out points.
__device__ __forceinline__ unsigned point_key(float xx, float xy, float xz) {
    if (fabsf(xx) < 1.5f && fabsf(xy) < 1.5f && fabsf(xz) < 1.5f) {
        float cx = fminf(fmaxf(xx / 1.5f, -1.f), 1.f);
        float cy = fminf(fmaxf(xy / 1.5f, -1.f), 1.f);
        float cz = fminf(fmaxf(xz / 1.5f, -1.f), 1.f);
        int ix = (int)(((cx + 1.f) * 0.5f) * (float)(RES - 1));
        int iy = (int)(((cy + 1.f) * 0.5f) * (float)(RES - 1));
        int iz = (int)(((cz + 1.f) * 0.5f) * (float)(RES - 1));
        ix = min(ix, RES - 1); iy = min(iy, RES - 1); iz = min(iz, RES - 1);
        return ((unsigned)(iz / BZC) * CY + (unsigned)(iy / BYC)) * CX + (unsigned)(ix / BXC);
    }
    return (unsigned)NCELLS;
}

__global__ __launch_bounds__(256) void k_count(const float* __restrict__ x,
                                               unsigned* __restrict__ key,
                                               unsigned* __restrict__ hist) {
    unsigned i = blockIdx.x * 256 + threadIdx.x;
    if (i >= N_PTS) return;
    float xx = x[3*i+0], xy = x[3*i+1], xz = x[3*i+2];
    unsigned k = point_key(xx, xy, xz);
    key[i] = k;
    if (k < (unsigned)NCELLS)
        atomicAdd(&hist[k * NPRIV + (blockIdx.x & (NPRIV - 1))], 1u);
    // masked points: no histogram slot, no perm slot — output is pre-zeroed.
}

// Single-block exclusive scan over HIST_ENTRIES entries; writes total valid
// count (= number of in-mask points) to *nvalid.
__global__ __launch_bounds__(1024) void k_scan(unsigned* __restrict__ hist,
                                               unsigned* __restrict__ nvalid) {
    __shared__ unsigned s[1024];
    const int TOT = HIST_ENTRIES;
    const int CHUNK = TOT / 1024;   // 54
    int t = threadIdx.x;
    int beg = t * CHUNK;
    int end = beg + CHUNK;
    unsigned sum = 0;
    for (int u = beg; u < end; ++u) sum += hist[u];
    s[t] = sum;
    __syncthreads();
    for (int off = 1; off < 1024; off *= 2) {
        unsigned v = (t >= off) ? s[t - off] : 0u;
        __syncthreads();
        s[t] += v;
        __syncthreads();
    }
    if (t == 1023) *nvalid = s[1023];
    unsigned run = (t > 0) ? s[t - 1] : 0u;
    for (int u = beg; u < end; ++u) {
        unsigned h = hist[u];
        hist[u] = run;
        run += h;
    }
}

__global__ __launch_bounds__(256) void k_scatter(const unsigned* __restrict__ key,
                                                 unsigned* __restrict__ hist,
                                                 unsigned* __restrict__ perm) {
    unsigned i = blockIdx.x * 256 + threadIdx.x;
    if (i >= N_PTS) return;
    unsigned k = key[i];
    if (k >= (unsigned)NCELLS) return;   // masked: not in perm
    unsigned pos = atomicAdd(&hist[k * NPRIV + (blockIdx.x & (NPRIV - 1))], 1u);
    if (pos < (unsigned)N_PTS) perm[pos] = i;
}

// ---------------------------------------------------------------------------
// Corner-parallel main, XCD-balanced. 4 threads per point; thread t owns the
// (y,z)-corner (t&1 -> y1, t&2 -> z1) and x-lerps it.
// Fixed grid of 4096 blocks; XCD k (= blockIdx.x & 7, HW round-robin) covers
// valid-quad range [k*nv/8, (k+1)*nv/8) — equal VALID work per XCD (round 8
// gave XCDs 5-7 almost nothing), contiguous per-XCD for L2 locality.
// All 28 channel pairs are loaded into static-index register arrays BEFORE
// combining: 56 outstanding loads/thread (vmcnt<=63) to fix the MLP
// starvation seen at VGPR_Count=36 (735 GB/s effective on 0.57 GB traffic).
// ---------------------------------------------------------------------------
__global__ __launch_bounds__(256, 4) void k_main4(const float* __restrict__ x,
                                                  const float* __restrict__ dvec,
                                                  const float* __restrict__ grid,
                                                  const unsigned* __restrict__ perm,
                                                  const unsigned* __restrict__ nvalid_p,
                                                  float* __restrict__ out) {
    unsigned nv  = *nvalid_p;                    // uniform scalar load
    unsigned xcd = blockIdx.x & 7;
    unsigned bx  = blockIdx.x >> 3;              // block index within XCD [0,512)
    unsigned q0  = (unsigned)(((unsigned long long)nv * xcd) >> 3);
    unsigned q1  = (unsigned)(((unsigned long long)nv * (xcd + 1)) >> 3);
    unsigned share = q1 - q0;
    unsigned chunk = (share + ((1u << BPX_SHIFT) - 1)) >> BPX_SHIFT;
    unsigned beg = q0 + bx * chunk;
    unsigned end = min(beg + chunk, q1);
    unsigned t   = threadIdx.x & 3;              // corner-pair id
    unsigned tq  = threadIdx.x >> 2;             // quad id within block [0,64)

    for (unsigned q = beg + tq; q < end; q += 64) {
        unsigned i = perm[q];
        if (i >= (unsigned)N_PTS) continue;      // defensive

        float xx = x[3*i+0], xy = x[3*i+1], xz = x[3*i+2];

        float cx = fminf(fmaxf(xx / 1.5f, -1.f), 1.f);
        float cy = fminf(fmaxf(xy / 1.5f, -1.f), 1.f);
        float cz = fminf(fmaxf(xz / 1.5f, -1.f), 1.f);
        float px = ((cx + 1.f) * 0.5f) * (float)(RES - 1);
        float py = ((cy + 1.f) * 0.5f) * (float)(RES - 1);
        float pz = ((cz + 1.f) * 0.5f) * (float)(RES - 1);
        float fx = floorf(px), fy = floorf(py), fz = floorf(pz);
        float wx = px - fx, wy = py - fy, wz = pz - fz;
        int ix0 = min((int)fx, RES - 1);
        int iy0 = min((int)fy, RES - 1);
        int iz0 = min((int)fz, RES - 1);
        int ix1 = min(ix0 + 1, RES - 1);
        int iy1 = min(iy0 + 1, RES - 1);
        int iz1 = min(iz0 + 1, RES - 1);

        int o000 = (iz0 * RES + iy0) * RES + ix0;
        int dX = ix1 - ix0;
        int dY = (iy1 - iy0) * RES;
        int dZ = (iz1 - iz0) * RES * RES;

        float mx = 1.f - wx, my = 1.f - wy, mz = 1.f - wz;

        // This thread's (y,z) corner:
        int   oA  = o000 + ((t & 1) ? dY : 0) + ((t & 2) ? dZ : 0);
        int   oB  = oA + dX;
        float wyz = ((t & 1) ? wy : my) * ((t & 2) ? wz : mz);
        float wA  = mx * wyz;
        float wB  = wx * wyz;

        // Load ALL channel pairs first (static indices -> registers, 56
        // loads in flight), then combine.
        float va[NCH], vb[NCH];
        {
            const float* g = grid;
            #pragma unroll
            for (int q2 = 0; q2 < NCH; ++q2) {
                va[q2] = g[oA];
                vb[q2] = g[oB];
                g += R3;
            }
        }

        float dx = dvec[3*i+0], dy = dvec[3*i+1], dz = dvec[3*i+2];
        float B[9];
        B[0] = 0.282095f;
        B[1] = -0.488603f * dy;
        B[2] =  0.488603f * dz;
        B[3] = -0.488603f * dx;
        B[4] =  1.092548f * dx * dy;
        B[5] = -1.092548f * dy * dz;
        B[6] =  0.315392f * (2.f * dz * dz - dx * dx - dy * dy);
        B[7] = -1.092548f * dx * dz;
        B[8] =  0.546274f * (dx * dx - dy * dy);

        float s  = wA * va[0] + wB * vb[0];
        float p0 = 0.f, p1 = 0.f, p2 = 0.f;
        #pragma unroll
        for (int q2 = 1; q2 < NCH; ++q2) {
            float v = wA * va[q2] + wB * vb[q2];
            int c = q2 - 1;
            float term = B[c % 9] * v;           // static after unroll
            if (c < 9)       p0 += term;
            else if (c < 18) p1 += term;
            else             p2 += term;
        }

        // Quad reduction (lanes t^1, t^2 within the same quad).
        s  += __shfl_xor(s, 1);  s  += __shfl_xor(s, 2);
        p0 += __shfl_xor(p0, 1); p0 += __shfl_xor(p0, 2);
        p1 += __shfl_xor(p1, 1); p1 += __shfl_xor(p1, 2);
        p2 += __shfl_xor(p2, 1); p2 += __shfl_xor(p2, 2);

        if (t == 0) {
            out[i]               = fmaxf(s, 0.f);
            out[N_PTS + 3*i + 0] = p0;
            out[N_PTS + 3*i + 1] = p1;
            out[N_PTS + 3*i + 2] = p2;
        }
    }
}

// Fallback (no workspace): one point per thread, unsorted, zeroes masked.
#define TRI(gp) (w000*(gp)[o000] + w001*(gp)[o001] + w010*(gp)[o010] + w011*(gp)[o011] \
               + w100*(gp)[o100] + w101*(gp)[o101] + w110*(gp)[o110] + w111*(gp)[o111])

__global__ __launch_bounds__(256, 4) void k_main_simple(const float* __restrict__ x,
                                                        const float* __restrict__ dvec,
                                                        const float* __restrict__ grid,
                                                        float* __restrict__ out) {
    unsigned i = blockIdx.x * 256 + threadIdx.x;
    if (i >= (unsigned)N_PTS) return;

    float xx = x[3*i+0], xy = x[3*i+1], xz = x[3*i+2];
    if (!(fabsf(xx) < 1.5f && fabsf(xy) < 1.5f && fabsf(xz) < 1.5f)) {
        out[i] = 0.f;
        out[N_PTS + 3*i + 0] = 0.f;
        out[N_PTS + 3*i + 1] = 0.f;
        out[N_PTS + 3*i + 2] = 0.f;
        return;
    }

    float cx = fminf(fmaxf(xx / 1.5f, -1.f), 1.f);
    float cy = fminf(fmaxf(xy / 1.5f, -1.f), 1.f);
    float cz = fminf(fmaxf(xz / 1.5f, -1.f), 1.f);
    float px = ((cx + 1.f) * 0.5f) * (float)(RES - 1);
    float py = ((cy + 1.f) * 0.5f) * (float)(RES - 1);
    float pz = ((cz + 1.f) * 0.5f) * (float)(RES - 1);
    float fx = floorf(px), fy = floorf(py), fz = floorf(pz);
    float wx = px - fx, wy = py - fy, wz = pz - fz;
    int ix0 = min((int)fx, RES - 1);
    int iy0 = min((int)fy, RES - 1);
    int iz0 = min((int)fz, RES - 1);
    int ix1 = min(ix0 + 1, RES - 1);
    int iy1 = min(iy0 + 1, RES - 1);
    int iz1 = min(iz0 + 1, RES - 1);

    int o000 = (iz0 * RES + iy0) * RES + ix0;
    int dX = ix1 - ix0;
    int dY = (iy1 - iy0) * RES;
    int dZ = (iz1 - iz0) * RES * RES;
    int o001 = o000 + dX,      o010 = o000 + dY,      o011 = o000 + dY + dX;
    int o100 = o000 + dZ,      o101 = o000 + dZ + dX;
    int o110 = o000 + dZ + dY, o111 = o000 + dZ + dY + dX;

    float mx = 1.f - wx, my = 1.f - wy, mz = 1.f - wz;
    float w000 = mx*my*mz, w001 = wx*my*mz, w010 = mx*wy*mz, w011 = wx*wy*mz;
    float w100 = mx*my*wz, w101 = wx*my*wz, w110 = mx*wy*wz, w111 = wx*wy*wz;

    const float* gp = grid;
    float sigma = fmaxf(TRI(gp), 0.f);

    float dx = dvec[3*i+0], dy = dvec[3*i+1], dz = dvec[3*i+2];
    float B[9];
    B[0] = 0.282095f;
    B[1] = -0.488603f * dy;
    B[2] =  0.488603f * dz;
    B[3] = -0.488603f * dx;
    B[4] =  1.092548f * dx * dy;
    B[5] = -1.092548f * dy * dz;
    B[6] =  0.315392f * (2.f * dz * dz - dx * dx - dy * dy);
    B[7] = -1.092548f * dx * dz;
    B[8] =  0.546274f * (dx * dx - dy * dy);

    float acc[3];
    #pragma unroll
    for (int gidx = 0; gidx < 3; ++gidx) {
        float a = 0.f;
        #pragma unroll
        for (int q = 0; q < 9; ++q) { gp += R3; a += B[q] * TRI(gp); }
        acc[gidx] = a;
    }

    out[i]               = sigma;
    out[N_PTS + 3*i + 0] = acc[0];
    out[N_PTS + 3*i + 1] = acc[1];
    out[N_PTS + 3*i + 2] = acc[2];
}

extern "C" void kernel_launch(void* const* d_in, const int* in_sizes, int n_in,
                              void* d_out, int out_size, void* d_ws, size_t ws_size,
                              hipStream_t stream) {
    // The voxel grid is the only huge input (28*192^3 elements); the two (N,3)
    // inputs keep their dict order: first = x (positions), second = d (dirs).
    int gi = -1;
    for (int i = 0; i < n_in; ++i) if (in_sizes[i] > 10000000) gi = i;
    int ai = -1, bi = -1;
    for (int i = 0; i < n_in; ++i) {
        if (i == gi) continue;
        if (ai < 0) ai = i; else if (bi < 0) bi = i;
    }
    const float* x    = (const float*)d_in[ai];
    const float* d    = (const float*)d_in[bi];
    const float* grid = (const float*)d_in[gi];
    float* out = (float*)d_out;

    const int NBLK = N_PTS / 256;   // 4096

    size_t need = (size_t)N_PTS * sizeof(unsigned) * 2
                + (size_t)HIST_ENTRIES * sizeof(unsigned) + sizeof(unsigned);
    bool do_sort = (d_ws != nullptr && ws_size >= need);

    // Masked points produce exactly 0: pre-zero the output and skip them.
    hipMemsetAsync(d_out, 0, (size_t)out_size * sizeof(float), stream);

    if (do_sort) {
        unsigned* perm   = (unsigned*)d_ws;
        unsigned* key    = perm + N_PTS;
        unsigned* hist   = key + N_PTS;
        unsigned* nvalid = hist + HIST_ENTRIES;
        hipMemsetAsync(hist, 0, HIST_ENTRIES * sizeof(unsigned), stream);
        hipMemsetAsync(perm, 0xFF, N_PTS * sizeof(unsigned), stream);   // sentinel
        k_count<<<NBLK, 256, 0, stream>>>(x, key, hist);
        k_scan<<<1, 1024, 0, stream>>>(hist, nvalid);
        k_scatter<<<NBLK, 256, 0, stream>>>(key, hist, perm);
        k_main4<<<MAIN_BLOCKS, 256, 0, stream>>>(x, d, grid, perm, nvalid, out);
    } else {
        k_main_simple<<<NBLK, 256, 0, stream>>>(x, d, grid, out);
    }
}

// Round 14
// 1416.424 us; speedup vs baseline: 1.1718x; 1.1371x over previous
//
#include <hip/hip_runtime.h>
#include <hip/hip_bf16.h>

#define N_PTS 1048576
#define RES 192
#define R3 (RES*RES*RES)
#define NCH 28

#define BXC 32
#define BYC 8
#define BZC 8
#define CX (RES/BXC)              // 6
#define CY (RES/BYC)              // 24
#define CZ (RES/BZC)              // 24
#define NCELLS (CX*CY*CZ)         // 3456
#define NPRIV 16                  // privatization for real cells
#define HIST_ENTRIES (NCELLS*NPRIV)   // 55296

#define MAIN_BLOCKS 16384         // 64 quads per block, 2048 blocks per XCD

// Returns cell id in [0, NCELLS) or NCELLS for masked-out points.
__device__ __forceinline__ unsigned point_key(float xx, float xy, float xz) {
    if (fabsf(xx) < 1.5f && fabsf(xy) < 1.5f && fabsf(xz) < 1.5f) {
        float cx = fminf(fmaxf(xx / 1.5f, -1.f), 1.f);
        float cy = fminf(fmaxf(xy / 1.5f, -1.f), 1.f);
        float cz = fminf(fmaxf(xz / 1.5f, -1.f), 1.f);
        int ix = (int)(((cx + 1.f) * 0.5f) * (float)(RES - 1));
        int iy = (int)(((cy + 1.f) * 0.5f) * (float)(RES - 1));
        int iz = (int)(((cz + 1.f) * 0.5f) * (float)(RES - 1));
        ix = min(ix, RES - 1); iy = min(iy, RES - 1); iz = min(iz, RES - 1);
        return ((unsigned)(iz / BZC) * CY + (unsigned)(iy / BYC)) * CX + (unsigned)(ix / BXC);
    }
    return (unsigned)NCELLS;
}

__global__ __launch_bounds__(256) void k_count(const float* __restrict__ x,
                                               unsigned* __restrict__ key,
                                               unsigned* __restrict__ hist) {
    unsigned i = blockIdx.x * 256 + threadIdx.x;
    if (i >= N_PTS) return;
    float xx = x[3*i+0], xy = x[3*i+1], xz = x[3*i+2];
    unsigned k = point_key(xx, xy, xz);
    key[i] = k;
    if (k < (unsigned)NCELLS)
        atomicAdd(&hist[k * NPRIV + (blockIdx.x & (NPRIV - 1))], 1u);
    // masked points: no histogram slot, no perm slot — output is pre-zeroed.
}

// Single-block exclusive scan over HIST_ENTRIES entries; writes total valid
// count (= number of in-mask points) to *nvalid.
__global__ __launch_bounds__(1024) void k_scan(unsigned* __restrict__ hist,
                                               unsigned* __restrict__ nvalid) {
    __shared__ unsigned s[1024];
    const int TOT = HIST_ENTRIES;
    const int CHUNK = TOT / 1024;   // 54
    int t = threadIdx.x;
    int beg = t * CHUNK;
    int end = beg + CHUNK;
    unsigned sum = 0;
    for (int u = beg; u < end; ++u) sum += hist[u];
    s[t] = sum;
    __syncthreads();
    for (int off = 1; off < 1024; off *= 2) {
        unsigned v = (t >= off) ? s[t - off] : 0u;
        __syncthreads();
        s[t] += v;
        __syncthreads();
    }
    if (t == 1023) *nvalid = s[1023];
    unsigned run = (t > 0) ? s[t - 1] : 0u;
    for (int u = beg; u < end; ++u) {
        unsigned h = hist[u];
        hist[u] = run;
        run += h;
    }
}

__global__ __launch_bounds__(256) void k_scatter(const unsigned* __restrict__ key,
                                                 unsigned* __restrict__ hist,
                                                 unsigned* __restrict__ perm) {
    unsigned i = blockIdx.x * 256 + threadIdx.x;
    if (i >= N_PTS) return;
    unsigned k = key[i];
    if (k >= (unsigned)NCELLS) return;   // masked: not in perm
    unsigned pos = atomicAdd(&hist[k * NPRIV + (blockIdx.x & (NPRIV - 1))], 1u);
    if (pos < (unsigned)N_PTS) perm[pos] = i;
}

// ---------------------------------------------------------------------------
// Corner-parallel main. 4 threads per point; thread t owns the (y,z)-corner
// (t&1 -> y1, t&2 -> z1) and x-lerps it.
//
// XCD balance + COMPACT window (round-8/11 lesson): 16384 fine-grained
// blocks of 64 quads, no loop. XCD k (= blockIdx&7, HW round-robin) covers
// valid range [k*nv/8,(k+1)*nv/8); within-XCD block b takes quads q0+64b...
// Resident blocks have consecutive b -> instantaneous working set per XCD is
// a narrow sliding window of sorted points (round 11's 512 long chunks
// widened the window 3.3x and FETCH rose 3.4x to 1.94 GB).
//
// MLP: all 28 channel pairs loaded BEFORE a sched_barrier(0); the barrier
// forbids the compiler from sinking loads into the combine (round 11:
// VGPR=32 proved it sank them, leaving ~few loads in flight).
// ---------------------------------------------------------------------------
__global__ __launch_bounds__(256, 4) void k_main4(const float* __restrict__ x,
                                                  const float* __restrict__ dvec,
                                                  const float* __restrict__ grid,
                                                  const unsigned* __restrict__ perm,
                                                  const unsigned* __restrict__ nvalid_p,
                                                  float* __restrict__ out) {
    unsigned nv  = *nvalid_p;                    // uniform scalar load
    unsigned xcd = blockIdx.x & 7;
    unsigned b   = blockIdx.x >> 3;              // block index within XCD [0,2048)
    unsigned q0  = (unsigned)(((unsigned long long)nv * xcd) >> 3);
    unsigned q1  = (unsigned)(((unsigned long long)nv * (xcd + 1)) >> 3);
    unsigned q   = q0 + b * 64u + (threadIdx.x >> 2);
    if (q >= q1) return;                         // trailing blocks idle out
    unsigned t   = threadIdx.x & 3;              // corner-pair id

    unsigned i = perm[q];
    if (i >= (unsigned)N_PTS) return;            // defensive

    float xx = x[3*i+0], xy = x[3*i+1], xz = x[3*i+2];

    float cx = fminf(fmaxf(xx / 1.5f, -1.f), 1.f);
    float cy = fminf(fmaxf(xy / 1.5f, -1.f), 1.f);
    float cz = fminf(fmaxf(xz / 1.5f, -1.f), 1.f);
    float px = ((cx + 1.f) * 0.5f) * (float)(RES - 1);
    float py = ((cy + 1.f) * 0.5f) * (float)(RES - 1);
    float pz = ((cz + 1.f) * 0.5f) * (float)(RES - 1);
    float fx = floorf(px), fy = floorf(py), fz = floorf(pz);
    float wx = px - fx, wy = py - fy, wz = pz - fz;
    int ix0 = min((int)fx, RES - 1);
    int iy0 = min((int)fy, RES - 1);
    int iz0 = min((int)fz, RES - 1);
    int ix1 = min(ix0 + 1, RES - 1);
    int iy1 = min(iy0 + 1, RES - 1);
    int iz1 = min(iz0 + 1, RES - 1);

    int o000 = (iz0 * RES + iy0) * RES + ix0;
    int dX = ix1 - ix0;
    int dY = (iy1 - iy0) * RES;
    int dZ = (iz1 - iz0) * RES * RES;

    float mx = 1.f - wx, my = 1.f - wy, mz = 1.f - wz;

    // This thread's (y,z) corner:
    int   oA  = o000 + ((t & 1) ? dY : 0) + ((t & 2) ? dZ : 0);
    int   oB  = oA + dX;
    float wyz = ((t & 1) ? wy : my) * ((t & 2) ? wz : mz);
    float wA  = mx * wyz;
    float wB  = wx * wyz;

    // Issue ALL 56 loads, then fence: sched_barrier(0) forbids sinking the
    // loads past it, so they are all in flight before the first use.
    float va[NCH], vb[NCH];
    {
        const float* g = grid;
        #pragma unroll
        for (int c = 0; c < NCH; ++c) {
            va[c] = g[oA];
            vb[c] = g[oB];
            g += R3;
        }
    }
    __builtin_amdgcn_sched_barrier(0);

    float dx = dvec[3*i+0], dy = dvec[3*i+1], dz = dvec[3*i+2];
    float B[9];
    B[0] = 0.282095f;
    B[1] = -0.488603f * dy;
    B[2] =  0.488603f * dz;
    B[3] = -0.488603f * dx;
    B[4] =  1.092548f * dx * dy;
    B[5] = -1.092548f * dy * dz;
    B[6] =  0.315392f * (2.f * dz * dz - dx * dx - dy * dy);
    B[7] = -1.092548f * dx * dz;
    B[8] =  0.546274f * (dx * dx - dy * dy);

    float s  = wA * va[0] + wB * vb[0];
    float p0 = 0.f, p1 = 0.f, p2 = 0.f;
    #pragma unroll
    for (int c2 = 1; c2 < NCH; ++c2) {
        float v = wA * va[c2] + wB * vb[c2];
        int c = c2 - 1;
        float term = B[c % 9] * v;               // static after unroll
        if (c < 9)       p0 += term;
        else if (c < 18) p1 += term;
        else             p2 += term;
    }

    // Quad reduction (lanes t^1, t^2 within the same quad).
    s  += __shfl_xor(s, 1);  s  += __shfl_xor(s, 2);
    p0 += __shfl_xor(p0, 1); p0 += __shfl_xor(p0, 2);
    p1 += __shfl_xor(p1, 1); p1 += __shfl_xor(p1, 2);
    p2 += __shfl_xor(p2, 1); p2 += __shfl_xor(p2, 2);

    if (t == 0) {
        out[i]               = fmaxf(s, 0.f);
        out[N_PTS + 3*i + 0] = p0;
        out[N_PTS + 3*i + 1] = p1;
        out[N_PTS + 3*i + 2] = p2;
    }
}

// Fallback (no workspace): one point per thread, unsorted, zeroes masked.
#define TRI(gp) (w000*(gp)[o000] + w001*(gp)[o001] + w010*(gp)[o010] + w011*(gp)[o011] \
               + w100*(gp)[o100] + w101*(gp)[o101] + w110*(gp)[o110] + w111*(gp)[o111])

__global__ __launch_bounds__(256, 4) void k_main_simple(const float* __restrict__ x,
                                                        const float* __restrict__ dvec,
                                                        const float* __restrict__ grid,
                                                        float* __restrict__ out) {
    unsigned i = blockIdx.x * 256 + threadIdx.x;
    if (i >= (unsigned)N_PTS) return;

    float xx = x[3*i+0], xy = x[3*i+1], xz = x[3*i+2];
    if (!(fabsf(xx) < 1.5f && fabsf(xy) < 1.5f && fabsf(xz) < 1.5f)) {
        out[i] = 0.f;
        out[N_PTS + 3*i + 0] = 0.f;
        out[N_PTS + 3*i + 1] = 0.f;
        out[N_PTS + 3*i + 2] = 0.f;
        return;
    }

    float cx = fminf(fmaxf(xx / 1.5f, -1.f), 1.f);
    float cy = fminf(fmaxf(xy / 1.5f, -1.f), 1.f);
    float cz = fminf(fmaxf(xz / 1.5f, -1.f), 1.f);
    float px = ((cx + 1.f) * 0.5f) * (float)(RES - 1);
    float py = ((cy + 1.f) * 0.5f) * (float)(RES - 1);
    float pz = ((cz + 1.f) * 0.5f) * (float)(RES - 1);
    float fx = floorf(px), fy = floorf(py), fz = floorf(pz);
    float wx = px - fx, wy = py - fy, wz = pz - fz;
    int ix0 = min((int)fx, RES - 1);
    int iy0 = min((int)fy, RES - 1);
    int iz0 = min((int)fz, RES - 1);
    int ix1 = min(ix0 + 1, RES - 1);
    int iy1 = min(iy0 + 1, RES - 1);
    int iz1 = min(iz0 + 1, RES - 1);

    int o000 = (iz0 * RES + iy0) * RES + ix0;
    int dX = ix1 - ix0;
    int dY = (iy1 - iy0) * RES;
    int dZ = (iz1 - iz0) * RES * RES;
    int o001 = o000 + dX,      o010 = o000 + dY,      o011 = o000 + dY + dX;
    int o100 = o000 + dZ,      o101 = o000 + dZ + dX;
    int o110 = o000 + dZ + dY, o111 = o000 + dZ + dY + dX;

    float mx = 1.f - wx, my = 1.f - wy, mz = 1.f - wz;
    float w000 = mx*my*mz, w001 = wx*my*mz, w010 = mx*wy*mz, w011 = wx*wy*mz;
    float w100 = mx*my*wz, w101 = wx*my*wz, w110 = mx*wy*wz, w111 = wx*wy*wz;

    const float* gp = grid;
    float sigma = fmaxf(TRI(gp), 0.f);

    float dx = dvec[3*i+0], dy = dvec[3*i+1], dz = dvec[3*i+2];
    float B[9];
    B[0] = 0.282095f;
    B[1] = -0.488603f * dy;
    B[2] =  0.488603f * dz;
    B[3] = -0.488603f * dx;
    B[4] =  1.092548f * dx * dy;
    B[5] = -1.092548f * dy * dz;
    B[6] =  0.315392f * (2.f * dz * dz - dx * dx - dy * dy);
    B[7] = -1.092548f * dx * dz;
    B[8] =  0.546274f * (dx * dx - dy * dy);

    float acc[3];
    #pragma unroll
    for (int gidx = 0; gidx < 3; ++gidx) {
        float a = 0.f;
        #pragma unroll
        for (int q = 0; q < 9; ++q) { gp += R3; a += B[q] * TRI(gp); }
        acc[gidx] = a;
    }

    out[i]               = sigma;
    out[N_PTS + 3*i + 0] = acc[0];
    out[N_PTS + 3*i + 1] = acc[1];
    out[N_PTS + 3*i + 2] = acc[2];
}

extern "C" void kernel_launch(void* const* d_in, const int* in_sizes, int n_in,
                              void* d_out, int out_size, void* d_ws, size_t ws_size,
                              hipStream_t stream) {
    // The voxel grid is the only huge input (28*192^3 elements); the two (N,3)
    // inputs keep their dict order: first = x (positions), second = d (dirs).
    int gi = -1;
    for (int i = 0; i < n_in; ++i) if (in_sizes[i] > 10000000) gi = i;
    int ai = -1, bi = -1;
    for (int i = 0; i < n_in; ++i) {
        if (i == gi) continue;
        if (ai < 0) ai = i; else if (bi < 0) bi = i;
    }
    const float* x    = (const float*)d_in[ai];
    const float* d    = (const float*)d_in[bi];
    const float* grid = (const float*)d_in[gi];
    float* out = (float*)d_out;

    const int NBLK = N_PTS / 256;   // 4096

    size_t need = (size_t)N_PTS * sizeof(unsigned) * 2
                + (size_t)HIST_ENTRIES * sizeof(unsigned) + sizeof(unsigned);
    bool do_sort = (d_ws != nullptr && ws_size >= need);

    // Masked points produce exactly 0: pre-zero the output and skip them.
    hipMemsetAsync(d_out, 0, (size_t)out_size * sizeof(float), stream);

    if (do_sort) {
        unsigned* perm   = (unsigned*)d_ws;
        unsigned* key    = perm + N_PTS;
        unsigned* hist   = key + N_PTS;
        unsigned* nvalid = hist + HIST_ENTRIES;
        hipMemsetAsync(hist, 0, HIST_ENTRIES * sizeof(unsigned), stream);
        hipMemsetAsync(perm, 0xFF, N_PTS * sizeof(unsigned), stream);   // sentinel
        k_count<<<NBLK, 256, 0, stream>>>(x, key, hist);
        k_scan<<<1, 1024, 0, stream>>>(hist, nvalid);
        k_scatter<<<NBLK, 256, 0, stream>>>(key, hist, perm);
        k_main4<<<MAIN_BLOCKS, 256, 0, stream>>>(x, d, grid, perm, nvalid, out);
    } else {
        k_main_simple<<<NBLK, 256, 0, stream>>>(x, d, grid, out);
    }
}